// Round 15
// baseline (140.401 us; speedup 1.0000x reference)
//
#include <hip/hip_runtime.h>

// GCN3: bucket-partition edges -> per-bucket counting sort -> CSR, then
// atomic-free gathers fused with dense transforms. Feature tables bf16.
// Gather: 4 lanes/node, lane loads uint4 (8 bf16) -> one wave64 instruction
// fetches 16 edge-rows (4 addr/edge). r15: revert to 8-deep batches (r14's
// 16-deep cut occupancy for no gain), keep pre-fusion + rowbuf reuse, and
// shrink fill chunks 8192->2048 for full-CU coverage.

#define RANGE_BITS 7
#define RANGE      128
#define MAXBK      1024
#define CHUNK      2048
#define FILL_T     512
#define CSR_T      256
#define CSR_CAP    4096
#define HIST_B     256

typedef unsigned short ushort_t;

__device__ __forceinline__ ushort_t f32_to_bf16(float x) {
    unsigned u = __float_as_uint(x);
    u += 0x7fffu + ((u >> 16) & 1u);    // RNE
    return (ushort_t)(u >> 16);
}
__device__ __forceinline__ float bf16_lo(unsigned w) {
    return __uint_as_float(w << 16);
}
__device__ __forceinline__ float bf16_hi(unsigned w) {
    return __uint_as_float(w & 0xffff0000u);
}

// ---------------- partition build ----------------

__global__ void zero_kernel(int* __restrict__ p, int count) {
    int i = blockIdx.x * blockDim.x + threadIdx.x;
    if (i < count) p[i] = 0;
}

// fused: blocks [0,HIST_B) histogram dst buckets; the rest convert x->bf16
__global__ void pre_kernel(const int* __restrict__ dst, int* __restrict__ ghist,
                           const float* __restrict__ xin, ushort_t* __restrict__ xb,
                           int nE, int nbk, int total8) {
    const int tid = threadIdx.x;
    if (blockIdx.x < HIST_B) {
        __shared__ int h[MAXBK];
        for (int i = tid; i < nbk; i += blockDim.x) h[i] = 0;
        __syncthreads();
        const int stride = HIST_B * blockDim.x;
        const int nv = nE >> 2;
        const uint4* d4 = (const uint4*)dst;
        for (int i = blockIdx.x * blockDim.x + tid; i < nv; i += stride) {
            uint4 v = d4[i];
            atomicAdd(&h[v.x >> RANGE_BITS], 1);
            atomicAdd(&h[v.y >> RANGE_BITS], 1);
            atomicAdd(&h[v.z >> RANGE_BITS], 1);
            atomicAdd(&h[v.w >> RANGE_BITS], 1);
        }
        for (int e = (nv << 2) + blockIdx.x * blockDim.x + tid; e < nE; e += stride)
            atomicAdd(&h[dst[e] >> RANGE_BITS], 1);
        __syncthreads();
        for (int i = tid; i < nbk; i += blockDim.x) {
            int c = h[i];
            if (c) atomicAdd(&ghist[i], c);
        }
    } else {
        int i = (blockIdx.x - HIST_B) * blockDim.x + tid;
        if (i >= total8) return;
        const float4* rp = (const float4*)(xin + (size_t)i * 8);
        float4 a = rp[0], b = rp[1];
        uint4 v;
        v.x = (unsigned)f32_to_bf16(a.x) | ((unsigned)f32_to_bf16(a.y) << 16);
        v.y = (unsigned)f32_to_bf16(a.z) | ((unsigned)f32_to_bf16(a.w) << 16);
        v.z = (unsigned)f32_to_bf16(b.x) | ((unsigned)f32_to_bf16(b.y) << 16);
        v.w = (unsigned)f32_to_bf16(b.z) | ((unsigned)f32_to_bf16(b.w) << 16);
        ((uint4*)(xb + (size_t)i * 8))[0] = v;
    }
}

__global__ void scan_kernel(int* __restrict__ ghist, int* __restrict__ boff,
                            int* __restrict__ gcur, int nbk) {
    __shared__ int lds[MAXBK];
    const int tid = threadIdx.x;
    for (int i = tid; i < nbk; i += blockDim.x) lds[i] = ghist[i];
    __syncthreads();
    for (int o = 1; o < nbk; o <<= 1) {
        int v = (tid >= o && tid < nbk) ? lds[tid - o] : 0;
        __syncthreads();
        if (tid < nbk) lds[tid] += v;
        __syncthreads();
    }
    if (tid < nbk) {
        int ex = (tid == 0) ? 0 : lds[tid - 1];
        boff[tid] = ex;
        gcur[tid] = ex;
        if (tid == nbk - 1) boff[nbk] = lds[tid];
    }
}

__global__ __launch_bounds__(FILL_T)
void fill_kernel(const int* __restrict__ src, const int* __restrict__ dst,
                 int* __restrict__ gcur, unsigned* __restrict__ edata,
                 int nE, int nbk) {
    __shared__ int cnt[MAXBK];
    __shared__ int base[MAXBK];
    const int tid = threadIdx.x;
    const int c0 = blockIdx.x * CHUNK;
    const int c1 = min(c0 + CHUNK, nE);
    for (int i = tid; i < nbk; i += FILL_T) cnt[i] = 0;
    __syncthreads();
    {
        const int full4 = (c1 - c0) >> 2;
        const uint4* d4 = (const uint4*)(dst + c0);
        for (int i = tid; i < full4; i += FILL_T) {
            uint4 v = d4[i];
            atomicAdd(&cnt[v.x >> RANGE_BITS], 1);
            atomicAdd(&cnt[v.y >> RANGE_BITS], 1);
            atomicAdd(&cnt[v.z >> RANGE_BITS], 1);
            atomicAdd(&cnt[v.w >> RANGE_BITS], 1);
        }
        for (int e = c0 + (full4 << 2) + tid; e < c1; e += FILL_T)
            atomicAdd(&cnt[dst[e] >> RANGE_BITS], 1);
    }
    __syncthreads();
    for (int i = tid; i < nbk; i += FILL_T) {
        int c = cnt[i];
        base[i] = c ? atomicAdd(&gcur[i], c) : 0;
        cnt[i] = 0;
    }
    __syncthreads();
    {
        const int full4 = (c1 - c0) >> 2;
        const uint4* d4 = (const uint4*)(dst + c0);
        const uint4* s4 = (const uint4*)(src + c0);
        for (int i = tid; i < full4; i += FILL_T) {
            uint4 dv = d4[i];
            uint4 sv = s4[i];
#pragma unroll
            for (int u = 0; u < 4; ++u) {
                unsigned d = (&dv.x)[u];
                unsigned s = (&sv.x)[u];
                int bk = (int)(d >> RANGE_BITS);
                int pos = base[bk] + atomicAdd(&cnt[bk], 1);
                edata[pos] = ((d & (RANGE - 1)) << 17) | s;
            }
        }
        for (int e = c0 + (full4 << 2) + tid; e < c1; e += FILL_T) {
            int d = dst[e];
            int bk = d >> RANGE_BITS;
            int pos = base[bk] + atomicAdd(&cnt[bk], 1);
            edata[pos] = ((unsigned)(d & (RANGE - 1)) << 17) | (unsigned)src[e];
        }
    }
}

__global__ __launch_bounds__(CSR_T)
void csr_kernel(const unsigned* __restrict__ edata, const int* __restrict__ boff,
                int* __restrict__ off, int* __restrict__ perm, int n, int nE) {
    __shared__ int hist[RANGE];
    __shared__ int loff[RANGE];
    __shared__ int cur[RANGE];
    __shared__ unsigned stage[CSR_CAP];
    const int tid = threadIdx.x;
    const int rid = blockIdx.x;
    const int e0  = boff[rid];
    const int cnt = boff[rid + 1] - e0;
    const bool fits = cnt <= CSR_CAP;

    if (tid < RANGE) hist[tid] = 0;
    __syncthreads();
    for (int i = tid; i < cnt; i += CSR_T) {
        unsigned p = edata[e0 + i];
        if (fits) stage[i] = p;
        atomicAdd(&hist[p >> 17], 1);
    }
    __syncthreads();
    if (tid < RANGE) loff[tid] = hist[tid];
    __syncthreads();
    for (int o = 1; o < RANGE; o <<= 1) {
        int v = (tid >= o && tid < RANGE) ? loff[tid - o] : 0;
        __syncthreads();
        if (tid < RANGE) loff[tid] += v;
        __syncthreads();
    }
    if (tid < RANGE) {
        int ex = loff[tid] - hist[tid];
        cur[tid] = ex;
        int node = (rid << RANGE_BITS) + tid;
        if (node < n) off[node] = e0 + ex;
    }
    if (tid == 0 && rid == gridDim.x - 1) off[n] = nE;
    __syncthreads();
    for (int i = tid; i < cnt; i += CSR_T) {
        unsigned p = fits ? stage[i] : edata[e0 + i];
        int pos = atomicAdd(&cur[p >> 17], 1);
        perm[e0 + pos] = (int)(p & 0x1ffffu);
    }
}

// ---------------- fused gather + dense: 4 lanes / node, uint4 rows ----------

__device__ __forceinline__ void acc_row(float* acc, const uint4& v) {
    acc[0] += bf16_lo(v.x); acc[1] += bf16_hi(v.x);
    acc[2] += bf16_lo(v.y); acc[3] += bf16_hi(v.y);
    acc[4] += bf16_lo(v.z); acc[5] += bf16_hi(v.z);
    acc[6] += bf16_lo(v.w); acc[7] += bf16_hi(v.w);
}

template <bool FUSE3>
__global__ __launch_bounds__(256)
void gather_dense_kernel(const ushort_t* __restrict__ t,   // [n][32] bf16
                         const int* __restrict__ perm,
                         const int* __restrict__ off,
                         const float* __restrict__ W,      // [32][32]
                         const float* __restrict__ b,      // [32]
                         const float* __restrict__ W3,     // [32][16] (FUSE3)
                         ushort_t* __restrict__ out,       // bf16
                         int n) {
    __shared__ float sW[32 * 32];
    __shared__ float sW3[32 * 16];
    __shared__ float rowbuf[64][33];    // 64 nodes/block, pad; reused twice
    const int tid = threadIdx.x;
    for (int i = tid; i < 32 * 32; i += 256) sW[i] = W[i];
    if (FUSE3)
        for (int i = tid; i < 32 * 16; i += 256) sW3[i] = W3[i];
    __syncthreads();

    const int gid  = blockIdx.x * 256 + tid;
    const int node = gid >> 2;
    const int f4   = gid & 3;           // 8-feature segment
    const int lrow = tid >> 2;          // local node 0..63
    if (node >= n) return;

    const int o = off[node];
    const int d = off[node + 1] - o;
    const int* __restrict__ pp = perm + o;

    float acc[8];
#pragma unroll
    for (int j = 0; j < 8; ++j) acc[j] = 0.0f;

    int base = 0;
    for (; base + 8 <= d; base += 8) {       // 8-deep: 8 uint4 in flight
        int pv0 = pp[base + f4];
        int pv1 = pp[base + 4 + f4];
        uint4 v[8];
#pragma unroll
        for (int u = 0; u < 4; ++u)
            v[u] = *((const uint4*)(t + ((size_t)__shfl(pv0, u, 4) << 5)) + f4);
#pragma unroll
        for (int u = 0; u < 4; ++u)
            v[4 + u] = *((const uint4*)(t + ((size_t)__shfl(pv1, u, 4) << 5)) + f4);
#pragma unroll
        for (int u = 0; u < 8; ++u) acc_row(acc, v[u]);
    }
    if (base + 4 <= d) {
        int pv = pp[base + f4];
        uint4 v[4];
#pragma unroll
        for (int u = 0; u < 4; ++u)
            v[u] = *((const uint4*)(t + ((size_t)__shfl(pv, u, 4) << 5)) + f4);
#pragma unroll
        for (int u = 0; u < 4; ++u) acc_row(acc, v[u]);
        base += 4;
    }
    for (; base < d; ++base) {               // broadcast remainder (<4)
        int s = pp[base];
        uint4 v = *((const uint4*)(t + ((size_t)s << 5)) + f4);
        acc_row(acc, v);
    }

    // wave-local row exchange (4-lane group owns its row; wave-lockstep safe)
#pragma unroll
    for (int j = 0; j < 8; ++j) rowbuf[lrow][f4 * 8 + j] = acc[j];

    float r[8];
#pragma unroll
    for (int j = 0; j < 8; ++j) r[j] = b[f4 * 8 + j];
#pragma unroll
    for (int k = 0; k < 32; ++k) {
        float a = rowbuf[lrow][k];
#pragma unroll
        for (int j = 0; j < 8; ++j) r[j] += a * sW[(k << 5) + f4 * 8 + j];
    }
#pragma unroll
    for (int j = 0; j < 8; ++j) r[j] = r[j] >= 0.0f ? r[j] : 0.1f * r[j];

    if (!FUSE3) {
        uint4 pk;
        pk.x = (unsigned)f32_to_bf16(r[0]) | ((unsigned)f32_to_bf16(r[1]) << 16);
        pk.y = (unsigned)f32_to_bf16(r[2]) | ((unsigned)f32_to_bf16(r[3]) << 16);
        pk.z = (unsigned)f32_to_bf16(r[4]) | ((unsigned)f32_to_bf16(r[5]) << 16);
        pk.w = (unsigned)f32_to_bf16(r[6]) | ((unsigned)f32_to_bf16(r[7]) << 16);
        ((uint4*)(out + ((size_t)node << 5)))[f4] = pk;
    } else {
        // second exchange reuses rowbuf (all first-pass reads retired: lockstep)
#pragma unroll
        for (int j = 0; j < 8; ++j) rowbuf[lrow][f4 * 8 + j] = r[j];
        float t3v[4];
#pragma unroll
        for (int m = 0; m < 4; ++m) t3v[m] = 0.0f;
#pragma unroll
        for (int k = 0; k < 32; ++k) {
            float a = rowbuf[lrow][k];
#pragma unroll
            for (int m = 0; m < 4; ++m) t3v[m] += a * sW3[(k << 4) + f4 * 4 + m];
        }
        uint2 pk;
        pk.x = (unsigned)f32_to_bf16(t3v[0]) | ((unsigned)f32_to_bf16(t3v[1]) << 16);
        pk.y = (unsigned)f32_to_bf16(t3v[2]) | ((unsigned)f32_to_bf16(t3v[3]) << 16);
        ((uint2*)(out + ((size_t)node << 4)))[f4] = pk;
    }
}

// layer 3: 2 lanes / node, uint4 rows (32 B), bias-init, fp32 out
__global__ __launch_bounds__(256)
void gather16_kernel(const ushort_t* __restrict__ t3,     // [n][16] bf16
                     const int* __restrict__ perm,
                     const int* __restrict__ off,
                     const float* __restrict__ b,         // [16]
                     float* __restrict__ out,             // [n][16] fp32
                     int n) {
    const int gid  = blockIdx.x * 256 + threadIdx.x;
    const int node = gid >> 1;
    const int f2   = gid & 1;           // 8-feature segment
    if (node >= n) return;

    const int o = off[node];
    const int d = off[node + 1] - o;
    const int* __restrict__ pp = perm + o;

    float acc[8];
#pragma unroll
    for (int j = 0; j < 8; ++j) acc[j] = b[f2 * 8 + j];

    int base = 0;
    for (; base + 8 <= d; base += 8) {
        int p0 = pp[base + f2];
        int p1 = pp[base + 2 + f2];
        int p2 = pp[base + 4 + f2];
        int p3 = pp[base + 6 + f2];
        uint4 v[8];
        v[0] = *((const uint4*)(t3 + ((size_t)__shfl(p0, 0, 2) << 4)) + f2);
        v[1] = *((const uint4*)(t3 + ((size_t)__shfl(p0, 1, 2) << 4)) + f2);
        v[2] = *((const uint4*)(t3 + ((size_t)__shfl(p1, 0, 2) << 4)) + f2);
        v[3] = *((const uint4*)(t3 + ((size_t)__shfl(p1, 1, 2) << 4)) + f2);
        v[4] = *((const uint4*)(t3 + ((size_t)__shfl(p2, 0, 2) << 4)) + f2);
        v[5] = *((const uint4*)(t3 + ((size_t)__shfl(p2, 1, 2) << 4)) + f2);
        v[6] = *((const uint4*)(t3 + ((size_t)__shfl(p3, 0, 2) << 4)) + f2);
        v[7] = *((const uint4*)(t3 + ((size_t)__shfl(p3, 1, 2) << 4)) + f2);
#pragma unroll
        for (int u = 0; u < 8; ++u) acc_row(acc, v[u]);
    }
    for (; base + 2 <= d; base += 2) {
        int p = pp[base + f2];
        uint4 v0 = *((const uint4*)(t3 + ((size_t)__shfl(p, 0, 2) << 4)) + f2);
        uint4 v1 = *((const uint4*)(t3 + ((size_t)__shfl(p, 1, 2) << 4)) + f2);
        acc_row(acc, v0);
        acc_row(acc, v1);
    }
    if (base < d) {
        int s = pp[base];
        uint4 v = *((const uint4*)(t3 + ((size_t)s << 4)) + f2);
        acc_row(acc, v);
    }

    float4 o0, o1;
    o0.x = acc[0]; o0.y = acc[1]; o0.z = acc[2]; o0.w = acc[3];
    o1.x = acc[4]; o1.y = acc[5]; o1.z = acc[6]; o1.w = acc[7];
    float4* op = (float4*)(out + ((size_t)node << 4) + f2 * 8);
    op[0] = o0;
    op[1] = o1;
}

// ---------------- fallback: atomic scatter path (fp32) ----------------

template <int F>
__global__ void scatter_kernel(const float* __restrict__ h, const int* __restrict__ src,
                               const int* __restrict__ dst, float* __restrict__ agg,
                               int n_edges) {
    int gid = blockIdx.x * blockDim.x + threadIdx.x;
    int e = gid / F, f = gid & (F - 1);
    if (e >= n_edges) return;
    unsafeAtomicAdd(&agg[(size_t)dst[e] * F + f], h[(size_t)src[e] * F + f]);
}

__global__ void zerof_kernel(float* __restrict__ p, int count) {
    int i = blockIdx.x * blockDim.x + threadIdx.x;
    if (i < count) p[i] = 0.0f;
}

template <int IN, int OUT, bool RELU>
__global__ void dense_bias_kernel(const float* __restrict__ in, const float* __restrict__ W,
                                  const float* __restrict__ b, float* __restrict__ out, int n) {
    __shared__ float sW[IN * OUT];
    __shared__ float sb[OUT];
    for (int i = threadIdx.x; i < IN * OUT; i += blockDim.x) sW[i] = W[i];
    for (int i = threadIdx.x; i < OUT; i += blockDim.x) sb[i] = b[i];
    __syncthreads();
    int node = blockIdx.x * blockDim.x + threadIdx.x;
    if (node >= n) return;
    float acc[OUT];
#pragma unroll
    for (int j = 0; j < OUT; ++j) acc[j] = sb[j];
#pragma unroll
    for (int k = 0; k < IN; ++k) {
        float a = in[(size_t)node * IN + k];
#pragma unroll
        for (int j = 0; j < OUT; ++j) acc[j] += a * sW[k * OUT + j];
    }
#pragma unroll
    for (int j = 0; j < OUT; ++j) {
        float v = acc[j];
        out[(size_t)node * OUT + j] = (RELU && v < 0.0f) ? 0.1f * v : v;
    }
}

template <int IN, int OUT>
__global__ void dense_kernel(const float* __restrict__ in, const float* __restrict__ W,
                             float* __restrict__ out, int n) {
    __shared__ float sW[IN * OUT];
    for (int i = threadIdx.x; i < IN * OUT; i += blockDim.x) sW[i] = W[i];
    __syncthreads();
    int node = blockIdx.x * blockDim.x + threadIdx.x;
    if (node >= n) return;
    float acc[OUT];
#pragma unroll
    for (int j = 0; j < OUT; ++j) acc[j] = 0.0f;
#pragma unroll
    for (int k = 0; k < IN; ++k) {
        float a = in[(size_t)node * IN + k];
#pragma unroll
        for (int j = 0; j < OUT; ++j) acc[j] += a * sW[k * OUT + j];
    }
#pragma unroll
    for (int j = 0; j < OUT; ++j) out[(size_t)node * OUT + j] = acc[j];
}

__global__ void init_out_kernel(float* __restrict__ out, const float* __restrict__ b,
                                int total) {
    int gid = blockIdx.x * blockDim.x + threadIdx.x;
    if (gid < total) out[gid] = b[gid & 15];
}

// ---------------- launch ----------------

extern "C" void kernel_launch(void* const* d_in, const int* in_sizes, int n_in,
                              void* d_out, int out_size, void* d_ws, size_t ws_size,
                              hipStream_t stream) {
    const float* x  = (const float*)d_in[0];
    const int* src  = (const int*)d_in[1];
    const int* dst  = (const int*)d_in[2];
    const float* W1 = (const float*)d_in[3];
    const float* b1 = (const float*)d_in[4];
    const float* W2 = (const float*)d_in[5];
    const float* b2 = (const float*)d_in[6];
    const float* W3 = (const float*)d_in[7];
    const float* b3 = (const float*)d_in[8];
    float* out = (float*)d_out;

    const int n  = in_sizes[0] / 32;    // 100000
    const int nE = in_sizes[1];         // 1600000
    const int nbk = (n + RANGE - 1) >> RANGE_BITS;   // 782

    unsigned* wsw   = (unsigned*)d_ws;
    ushort_t* xb    = (ushort_t*)wsw;                      // n*32 bf16
    ushort_t* h1b   = (ushort_t*)(wsw + (size_t)n * 16);   // n*32 bf16
    ushort_t* t3b   = (ushort_t*)(wsw + (size_t)n * 32);   // n*16 bf16
    unsigned* edata = wsw + (size_t)n * 40;                // nE
    int*      perm  = (int*)(edata + nE);                  // nE
    int*      off   = perm + nE;                           // n+1
    int*      boff  = off + n + 1;                         // nbk+1
    int*      gcur  = boff + nbk + 1;                      // nbk
    size_t need = ((size_t)n * 40 + 2 * (size_t)nE + (size_t)n + 2 * (size_t)nbk + 2) * 4;

    if (ws_size >= need && nbk <= MAXBK && n < (1 << 17) && (n * 32) % 8 == 0) {
        const int total8 = n * 32 / 8;
        const int cvt_blocks = (total8 + 255) / 256;
        zero_kernel<<<(nbk + 255) / 256, 256, 0, stream>>>(gcur, nbk);
        pre_kernel<<<HIST_B + cvt_blocks, 256, 0, stream>>>(dst, gcur, x, xb, nE, nbk, total8);
        scan_kernel<<<1, 1024, 0, stream>>>(gcur, boff, gcur, nbk);
        fill_kernel<<<(nE + CHUNK - 1) / CHUNK, FILL_T, 0, stream>>>(src, dst, gcur, edata, nE, nbk);
        csr_kernel<<<nbk, CSR_T, 0, stream>>>(edata, boff, off, perm, n, nE);

        const int g4 = (n * 4 + 255) / 256;
        const int g2 = (n * 2 + 255) / 256;
        // layer 1: h1b = bf16(leaky(agg(xb) @ W1 + b1))
        gather_dense_kernel<false><<<g4, 256, 0, stream>>>(xb, perm, off, W1, b1, nullptr, h1b, n);
        // layer 2 (+W3 fused): t3b = bf16(leaky(agg(h1b) @ W2 + b2) @ W3)
        gather_dense_kernel<true><<<g4, 256, 0, stream>>>(h1b, perm, off, W2, b2, W3, t3b, n);
        // layer 3: out = agg(t3b) + b3   (fp32 output)
        gather16_kernel<<<g2, 256, 0, stream>>>(t3b, perm, off, b3, out, n);
    } else {
        const int BLK = 256;
        const int node_grid = (n + BLK - 1) / BLK;
        float* agg = (float*)d_ws;
        float* h   = agg + (size_t)n * 32;
        zerof_kernel<<<(n * 32 + BLK - 1) / BLK, BLK, 0, stream>>>(agg, n * 32);
        scatter_kernel<32><<<((size_t)nE * 32 + BLK - 1) / BLK, BLK, 0, stream>>>(x, src, dst, agg, nE);
        dense_bias_kernel<32, 32, true><<<node_grid, BLK, 0, stream>>>(agg, W1, b1, h, n);
        zerof_kernel<<<(n * 32 + BLK - 1) / BLK, BLK, 0, stream>>>(agg, n * 32);
        scatter_kernel<32><<<((size_t)nE * 32 + BLK - 1) / BLK, BLK, 0, stream>>>(h, src, dst, agg, nE);
        dense_bias_kernel<32, 32, true><<<node_grid, BLK, 0, stream>>>(agg, W2, b2, h, n);
        dense_kernel<32, 16><<<node_grid, BLK, 0, stream>>>(h, W3, agg, n);
        init_out_kernel<<<(n * 16 + BLK - 1) / BLK, BLK, 0, stream>>>(out, b3, n * 16);
        scatter_kernel<16><<<((size_t)nE * 16 + BLK - 1) / BLK, BLK, 0, stream>>>(agg, src, dst, out, nE);
    }
}

// Round 16
// 125.348 us; speedup vs baseline: 1.1201x; 1.1201x over previous
//
#include <hip/hip_runtime.h>

// GCN3: bucket-partition edges -> per-bucket counting sort -> CSR, then
// atomic-free gathers fused with dense transforms. Feature tables bf16.
// Gather layout: 4 lanes per node, each lane loads uint4 (8 bf16) -> one
// wave64 gather instruction fetches 16 edge-rows (4 addresses/edge).
// r16 == r13 exactly (best measured: 126.4 us). r14's 16-deep batches
// (-occupancy, neutral) and r15's CHUNK=2048 (+fill overhead, -12 us)
// both regressed; this locks in the verified optimum.

#define RANGE_BITS 7
#define RANGE      128
#define MAXBK      1024
#define CHUNK      8192
#define FILL_T     512
#define CSR_T      256
#define CSR_CAP    4096

typedef unsigned short ushort_t;

__device__ __forceinline__ ushort_t f32_to_bf16(float x) {
    unsigned u = __float_as_uint(x);
    u += 0x7fffu + ((u >> 16) & 1u);    // RNE
    return (ushort_t)(u >> 16);
}
__device__ __forceinline__ float bf16_lo(unsigned w) {
    return __uint_as_float(w << 16);
}
__device__ __forceinline__ float bf16_hi(unsigned w) {
    return __uint_as_float(w & 0xffff0000u);
}

// ---------------- partition build ----------------

__global__ void zero_kernel(int* __restrict__ p, int count) {
    int i = blockIdx.x * blockDim.x + threadIdx.x;
    if (i < count) p[i] = 0;
}

__global__ void hist_kernel(const int* __restrict__ dst, int* __restrict__ ghist,
                            int nE, int nbk) {
    __shared__ int h[MAXBK];
    const int tid = threadIdx.x;
    for (int i = tid; i < nbk; i += blockDim.x) h[i] = 0;
    __syncthreads();
    const int stride = gridDim.x * blockDim.x;
    const int nv = nE >> 2;
    const uint4* d4 = (const uint4*)dst;
    for (int i = blockIdx.x * blockDim.x + tid; i < nv; i += stride) {
        uint4 v = d4[i];
        atomicAdd(&h[v.x >> RANGE_BITS], 1);
        atomicAdd(&h[v.y >> RANGE_BITS], 1);
        atomicAdd(&h[v.z >> RANGE_BITS], 1);
        atomicAdd(&h[v.w >> RANGE_BITS], 1);
    }
    for (int e = (nv << 2) + blockIdx.x * blockDim.x + tid; e < nE; e += stride)
        atomicAdd(&h[dst[e] >> RANGE_BITS], 1);
    __syncthreads();
    for (int i = tid; i < nbk; i += blockDim.x) {
        int c = h[i];
        if (c) atomicAdd(&ghist[i], c);
    }
}

__global__ void scan_kernel(int* __restrict__ ghist, int* __restrict__ boff,
                            int* __restrict__ gcur, int nbk) {
    __shared__ int lds[MAXBK];
    const int tid = threadIdx.x;
    for (int i = tid; i < nbk; i += blockDim.x) lds[i] = ghist[i];
    __syncthreads();
    for (int o = 1; o < nbk; o <<= 1) {
        int v = (tid >= o && tid < nbk) ? lds[tid - o] : 0;
        __syncthreads();
        if (tid < nbk) lds[tid] += v;
        __syncthreads();
    }
    if (tid < nbk) {
        int ex = (tid == 0) ? 0 : lds[tid - 1];
        boff[tid] = ex;
        gcur[tid] = ex;
        if (tid == nbk - 1) boff[nbk] = lds[tid];
    }
}

__global__ __launch_bounds__(FILL_T)
void fill_kernel(const int* __restrict__ src, const int* __restrict__ dst,
                 int* __restrict__ gcur, unsigned* __restrict__ edata,
                 int nE, int nbk) {
    __shared__ int cnt[MAXBK];
    __shared__ int base[MAXBK];
    const int tid = threadIdx.x;
    const int c0 = blockIdx.x * CHUNK;
    const int c1 = min(c0 + CHUNK, nE);
    for (int i = tid; i < nbk; i += FILL_T) cnt[i] = 0;
    __syncthreads();
    {
        const int full4 = (c1 - c0) >> 2;
        const uint4* d4 = (const uint4*)(dst + c0);
        for (int i = tid; i < full4; i += FILL_T) {
            uint4 v = d4[i];
            atomicAdd(&cnt[v.x >> RANGE_BITS], 1);
            atomicAdd(&cnt[v.y >> RANGE_BITS], 1);
            atomicAdd(&cnt[v.z >> RANGE_BITS], 1);
            atomicAdd(&cnt[v.w >> RANGE_BITS], 1);
        }
        for (int e = c0 + (full4 << 2) + tid; e < c1; e += FILL_T)
            atomicAdd(&cnt[dst[e] >> RANGE_BITS], 1);
    }
    __syncthreads();
    for (int i = tid; i < nbk; i += FILL_T) {
        int c = cnt[i];
        base[i] = c ? atomicAdd(&gcur[i], c) : 0;
        cnt[i] = 0;
    }
    __syncthreads();
    {
        const int full4 = (c1 - c0) >> 2;
        const uint4* d4 = (const uint4*)(dst + c0);
        const uint4* s4 = (const uint4*)(src + c0);
        for (int i = tid; i < full4; i += FILL_T) {
            uint4 dv = d4[i];
            uint4 sv = s4[i];
#pragma unroll
            for (int u = 0; u < 4; ++u) {
                unsigned d = (&dv.x)[u];
                unsigned s = (&sv.x)[u];
                int bk = (int)(d >> RANGE_BITS);
                int pos = base[bk] + atomicAdd(&cnt[bk], 1);
                edata[pos] = ((d & (RANGE - 1)) << 17) | s;
            }
        }
        for (int e = c0 + (full4 << 2) + tid; e < c1; e += FILL_T) {
            int d = dst[e];
            int bk = d >> RANGE_BITS;
            int pos = base[bk] + atomicAdd(&cnt[bk], 1);
            edata[pos] = ((unsigned)(d & (RANGE - 1)) << 17) | (unsigned)src[e];
        }
    }
}

__global__ __launch_bounds__(CSR_T)
void csr_kernel(const unsigned* __restrict__ edata, const int* __restrict__ boff,
                int* __restrict__ off, int* __restrict__ perm, int n, int nE) {
    __shared__ int hist[RANGE];
    __shared__ int loff[RANGE];
    __shared__ int cur[RANGE];
    __shared__ unsigned stage[CSR_CAP];
    const int tid = threadIdx.x;
    const int rid = blockIdx.x;
    const int e0  = boff[rid];
    const int cnt = boff[rid + 1] - e0;
    const bool fits = cnt <= CSR_CAP;

    if (tid < RANGE) hist[tid] = 0;
    __syncthreads();
    for (int i = tid; i < cnt; i += CSR_T) {
        unsigned p = edata[e0 + i];
        if (fits) stage[i] = p;
        atomicAdd(&hist[p >> 17], 1);
    }
    __syncthreads();
    if (tid < RANGE) loff[tid] = hist[tid];
    __syncthreads();
    for (int o = 1; o < RANGE; o <<= 1) {
        int v = (tid >= o && tid < RANGE) ? loff[tid - o] : 0;
        __syncthreads();
        if (tid < RANGE) loff[tid] += v;
        __syncthreads();
    }
    if (tid < RANGE) {
        int ex = loff[tid] - hist[tid];
        cur[tid] = ex;
        int node = (rid << RANGE_BITS) + tid;
        if (node < n) off[node] = e0 + ex;
    }
    if (tid == 0 && rid == gridDim.x - 1) off[n] = nE;
    __syncthreads();
    for (int i = tid; i < cnt; i += CSR_T) {
        unsigned p = fits ? stage[i] : edata[e0 + i];
        int pos = atomicAdd(&cur[p >> 17], 1);
        perm[e0 + pos] = (int)(p & 0x1ffffu);
    }
}

// ---------------- fp32 -> bf16 table convert ----------------

__global__ void cvt_bf16_kernel(const float* __restrict__ in,
                                ushort_t* __restrict__ out, int total8) {
    int i = blockIdx.x * blockDim.x + threadIdx.x;
    if (i >= total8) return;
    const float4* rp = (const float4*)(in + (size_t)i * 8);
    float4 a = rp[0], b = rp[1];
    uint4 v;
    v.x = (unsigned)f32_to_bf16(a.x) | ((unsigned)f32_to_bf16(a.y) << 16);
    v.y = (unsigned)f32_to_bf16(a.z) | ((unsigned)f32_to_bf16(a.w) << 16);
    v.z = (unsigned)f32_to_bf16(b.x) | ((unsigned)f32_to_bf16(b.y) << 16);
    v.w = (unsigned)f32_to_bf16(b.z) | ((unsigned)f32_to_bf16(b.w) << 16);
    ((uint4*)(out + (size_t)i * 8))[0] = v;
}

// ---------------- fused gather + dense: 4 lanes / node, uint4 rows ----------

__device__ __forceinline__ void acc_row(float* acc, const uint4& v) {
    acc[0] += bf16_lo(v.x); acc[1] += bf16_hi(v.x);
    acc[2] += bf16_lo(v.y); acc[3] += bf16_hi(v.y);
    acc[4] += bf16_lo(v.z); acc[5] += bf16_hi(v.z);
    acc[6] += bf16_lo(v.w); acc[7] += bf16_hi(v.w);
}

template <bool FUSE3>
__global__ __launch_bounds__(256)
void gather_dense_kernel(const ushort_t* __restrict__ t,   // [n][32] bf16
                         const int* __restrict__ perm,
                         const int* __restrict__ off,
                         const float* __restrict__ W,      // [32][32]
                         const float* __restrict__ b,      // [32]
                         const float* __restrict__ W3,     // [32][16] (FUSE3)
                         ushort_t* __restrict__ out,       // bf16
                         int n) {
    __shared__ float sW[32 * 32];
    __shared__ float sW3[32 * 16];
    __shared__ float rowbuf[64][33];    // 64 nodes/block, pad
    __shared__ float rowbuf2[64][33];
    const int tid = threadIdx.x;
    for (int i = tid; i < 32 * 32; i += 256) sW[i] = W[i];
    if (FUSE3)
        for (int i = tid; i < 32 * 16; i += 256) sW3[i] = W3[i];
    __syncthreads();

    const int gid  = blockIdx.x * 256 + tid;
    const int node = gid >> 2;
    const int f4   = gid & 3;           // 8-feature segment
    const int lrow = tid >> 2;          // local node 0..63
    if (node >= n) return;

    const int o = off[node];
    const int d = off[node + 1] - o;
    const int* __restrict__ pp = perm + o;

    float acc[8];
#pragma unroll
    for (int j = 0; j < 8; ++j) acc[j] = 0.0f;

    int base = 0;
    for (; base + 8 <= d; base += 8) {       // 8-deep: 8 uint4 in flight
        int pv0 = pp[base + f4];
        int pv1 = pp[base + 4 + f4];
        uint4 v[8];
#pragma unroll
        for (int u = 0; u < 4; ++u) {
            int s = __shfl(pv0, u, 4);
            v[u] = *((const uint4*)(t + ((size_t)s << 5)) + f4);
        }
#pragma unroll
        for (int u = 0; u < 4; ++u) {
            int s = __shfl(pv1, u, 4);
            v[4 + u] = *((const uint4*)(t + ((size_t)s << 5)) + f4);
        }
#pragma unroll
        for (int u = 0; u < 8; ++u) acc_row(acc, v[u]);
    }
    if (base + 4 <= d) {
        int pv = pp[base + f4];
        uint4 v[4];
#pragma unroll
        for (int u = 0; u < 4; ++u) {
            int s = __shfl(pv, u, 4);
            v[u] = *((const uint4*)(t + ((size_t)s << 5)) + f4);
        }
#pragma unroll
        for (int u = 0; u < 4; ++u) acc_row(acc, v[u]);
        base += 4;
    }
    for (; base < d; ++base) {               // broadcast remainder (<4)
        int s = pp[base];
        uint4 v = *((const uint4*)(t + ((size_t)s << 5)) + f4);
        acc_row(acc, v);
    }

    // wave-local row exchange (4-lane group owns its row)
#pragma unroll
    for (int j = 0; j < 8; ++j) rowbuf[lrow][f4 * 8 + j] = acc[j];

    float r[8];
#pragma unroll
    for (int j = 0; j < 8; ++j) r[j] = b[f4 * 8 + j];
#pragma unroll
    for (int k = 0; k < 32; ++k) {
        float a = rowbuf[lrow][k];
#pragma unroll
        for (int j = 0; j < 8; ++j) r[j] += a * sW[(k << 5) + f4 * 8 + j];
    }
#pragma unroll
    for (int j = 0; j < 8; ++j) r[j] = r[j] >= 0.0f ? r[j] : 0.1f * r[j];

    if (!FUSE3) {
        uint4 pk;
        pk.x = (unsigned)f32_to_bf16(r[0]) | ((unsigned)f32_to_bf16(r[1]) << 16);
        pk.y = (unsigned)f32_to_bf16(r[2]) | ((unsigned)f32_to_bf16(r[3]) << 16);
        pk.z = (unsigned)f32_to_bf16(r[4]) | ((unsigned)f32_to_bf16(r[5]) << 16);
        pk.w = (unsigned)f32_to_bf16(r[6]) | ((unsigned)f32_to_bf16(r[7]) << 16);
        ((uint4*)(out + ((size_t)node << 5)))[f4] = pk;
    } else {
#pragma unroll
        for (int j = 0; j < 8; ++j) rowbuf2[lrow][f4 * 8 + j] = r[j];
        float t3v[4];
#pragma unroll
        for (int m = 0; m < 4; ++m) t3v[m] = 0.0f;
#pragma unroll
        for (int k = 0; k < 32; ++k) {
            float a = rowbuf2[lrow][k];
#pragma unroll
            for (int m = 0; m < 4; ++m) t3v[m] += a * sW3[(k << 4) + f4 * 4 + m];
        }
        uint2 pk;
        pk.x = (unsigned)f32_to_bf16(t3v[0]) | ((unsigned)f32_to_bf16(t3v[1]) << 16);
        pk.y = (unsigned)f32_to_bf16(t3v[2]) | ((unsigned)f32_to_bf16(t3v[3]) << 16);
        ((uint2*)(out + ((size_t)node << 4)))[f4] = pk;
    }
}

// layer 3: 2 lanes / node, uint4 rows (32 B), bias-init, fp32 out
__global__ __launch_bounds__(256)
void gather16_kernel(const ushort_t* __restrict__ t3,     // [n][16] bf16
                     const int* __restrict__ perm,
                     const int* __restrict__ off,
                     const float* __restrict__ b,         // [16]
                     float* __restrict__ out,             // [n][16] fp32
                     int n) {
    const int gid  = blockIdx.x * 256 + threadIdx.x;
    const int node = gid >> 1;
    const int f2   = gid & 1;           // 8-feature segment
    if (node >= n) return;

    const int o = off[node];
    const int d = off[node + 1] - o;
    const int* __restrict__ pp = perm + o;

    float acc[8];
#pragma unroll
    for (int j = 0; j < 8; ++j) acc[j] = b[f2 * 8 + j];

    int base = 0;
    for (; base + 8 <= d; base += 8) {
        int p0 = pp[base + f2];
        int p1 = pp[base + 2 + f2];
        int p2 = pp[base + 4 + f2];
        int p3 = pp[base + 6 + f2];
        uint4 v[8];
        v[0] = *((const uint4*)(t3 + ((size_t)__shfl(p0, 0, 2) << 4)) + f2);
        v[1] = *((const uint4*)(t3 + ((size_t)__shfl(p0, 1, 2) << 4)) + f2);
        v[2] = *((const uint4*)(t3 + ((size_t)__shfl(p1, 0, 2) << 4)) + f2);
        v[3] = *((const uint4*)(t3 + ((size_t)__shfl(p1, 1, 2) << 4)) + f2);
        v[4] = *((const uint4*)(t3 + ((size_t)__shfl(p2, 0, 2) << 4)) + f2);
        v[5] = *((const uint4*)(t3 + ((size_t)__shfl(p2, 1, 2) << 4)) + f2);
        v[6] = *((const uint4*)(t3 + ((size_t)__shfl(p3, 0, 2) << 4)) + f2);
        v[7] = *((const uint4*)(t3 + ((size_t)__shfl(p3, 1, 2) << 4)) + f2);
#pragma unroll
        for (int u = 0; u < 8; ++u) acc_row(acc, v[u]);
    }
    for (; base + 2 <= d; base += 2) {
        int p = pp[base + f2];
        uint4 v0 = *((const uint4*)(t3 + ((size_t)__shfl(p, 0, 2) << 4)) + f2);
        uint4 v1 = *((const uint4*)(t3 + ((size_t)__shfl(p, 1, 2) << 4)) + f2);
        acc_row(acc, v0);
        acc_row(acc, v1);
    }
    if (base < d) {
        int s = pp[base];
        uint4 v = *((const uint4*)(t3 + ((size_t)s << 4)) + f2);
        acc_row(acc, v);
    }

    float4 o0, o1;
    o0.x = acc[0]; o0.y = acc[1]; o0.z = acc[2]; o0.w = acc[3];
    o1.x = acc[4]; o1.y = acc[5]; o1.z = acc[6]; o1.w = acc[7];
    float4* op = (float4*)(out + ((size_t)node << 4) + f2 * 8);
    op[0] = o0;
    op[1] = o1;
}

// ---------------- fallback: atomic scatter path (fp32) ----------------

template <int F>
__global__ void scatter_kernel(const float* __restrict__ h, const int* __restrict__ src,
                               const int* __restrict__ dst, float* __restrict__ agg,
                               int n_edges) {
    int gid = blockIdx.x * blockDim.x + threadIdx.x;
    int e = gid / F, f = gid & (F - 1);
    if (e >= n_edges) return;
    unsafeAtomicAdd(&agg[(size_t)dst[e] * F + f], h[(size_t)src[e] * F + f]);
}

__global__ void zerof_kernel(float* __restrict__ p, int count) {
    int i = blockIdx.x * blockDim.x + threadIdx.x;
    if (i < count) p[i] = 0.0f;
}

template <int IN, int OUT, bool RELU>
__global__ void dense_bias_kernel(const float* __restrict__ in, const float* __restrict__ W,
                                  const float* __restrict__ b, float* __restrict__ out, int n) {
    __shared__ float sW[IN * OUT];
    __shared__ float sb[OUT];
    for (int i = threadIdx.x; i < IN * OUT; i += blockDim.x) sW[i] = W[i];
    for (int i = threadIdx.x; i < OUT; i += blockDim.x) sb[i] = b[i];
    __syncthreads();
    int node = blockIdx.x * blockDim.x + threadIdx.x;
    if (node >= n) return;
    float acc[OUT];
#pragma unroll
    for (int j = 0; j < OUT; ++j) acc[j] = sb[j];
#pragma unroll
    for (int k = 0; k < IN; ++k) {
        float a = in[(size_t)node * IN + k];
#pragma unroll
        for (int j = 0; j < OUT; ++j) acc[j] += a * sW[k * OUT + j];
    }
#pragma unroll
    for (int j = 0; j < OUT; ++j) {
        float v = acc[j];
        out[(size_t)node * OUT + j] = (RELU && v < 0.0f) ? 0.1f * v : v;
    }
}

template <int IN, int OUT>
__global__ void dense_kernel(const float* __restrict__ in, const float* __restrict__ W,
                             float* __restrict__ out, int n) {
    __shared__ float sW[IN * OUT];
    for (int i = threadIdx.x; i < IN * OUT; i += blockDim.x) sW[i] = W[i];
    __syncthreads();
    int node = blockIdx.x * blockDim.x + threadIdx.x;
    if (node >= n) return;
    float acc[OUT];
#pragma unroll
    for (int j = 0; j < OUT; ++j) acc[j] = 0.0f;
#pragma unroll
    for (int k = 0; k < IN; ++k) {
        float a = in[(size_t)node * IN + k];
#pragma unroll
        for (int j = 0; j < OUT; ++j) acc[j] += a * sW[k * OUT + j];
    }
#pragma unroll
    for (int j = 0; j < OUT; ++j) out[(size_t)node * OUT + j] = acc[j];
}

__global__ void init_out_kernel(float* __restrict__ out, const float* __restrict__ b,
                                int total) {
    int gid = blockIdx.x * blockDim.x + threadIdx.x;
    if (gid < total) out[gid] = b[gid & 15];
}

// ---------------- launch ----------------

extern "C" void kernel_launch(void* const* d_in, const int* in_sizes, int n_in,
                              void* d_out, int out_size, void* d_ws, size_t ws_size,
                              hipStream_t stream) {
    const float* x  = (const float*)d_in[0];
    const int* src  = (const int*)d_in[1];
    const int* dst  = (const int*)d_in[2];
    const float* W1 = (const float*)d_in[3];
    const float* b1 = (const float*)d_in[4];
    const float* W2 = (const float*)d_in[5];
    const float* b2 = (const float*)d_in[6];
    const float* W3 = (const float*)d_in[7];
    const float* b3 = (const float*)d_in[8];
    float* out = (float*)d_out;

    const int n  = in_sizes[0] / 32;    // 100000
    const int nE = in_sizes[1];         // 1600000
    const int nbk = (n + RANGE - 1) >> RANGE_BITS;   // 782

    unsigned* wsw   = (unsigned*)d_ws;
    ushort_t* xb    = (ushort_t*)wsw;                      // n*32 bf16
    ushort_t* h1b   = (ushort_t*)(wsw + (size_t)n * 16);   // n*32 bf16
    ushort_t* t3b   = (ushort_t*)(wsw + (size_t)n * 32);   // n*16 bf16
    unsigned* edata = wsw + (size_t)n * 40;                // nE
    int*      perm  = (int*)(edata + nE);                  // nE
    int*      off   = perm + nE;                           // n+1
    int*      boff  = off + n + 1;                         // nbk+1
    int*      gcur  = boff + nbk + 1;                      // nbk
    size_t need = ((size_t)n * 40 + 2 * (size_t)nE + (size_t)n + 2 * (size_t)nbk + 2) * 4;

    if (ws_size >= need && nbk <= MAXBK && n < (1 << 17) && (n * 32) % 8 == 0) {
        zero_kernel<<<(nbk + 255) / 256, 256, 0, stream>>>(gcur, nbk);
        hist_kernel<<<256, 512, 0, stream>>>(dst, gcur, nE, nbk);
        cvt_bf16_kernel<<<(n * 32 / 8 + 255) / 256, 256, 0, stream>>>(x, xb, n * 32 / 8);
        scan_kernel<<<1, 1024, 0, stream>>>(gcur, boff, gcur, nbk);
        fill_kernel<<<(nE + CHUNK - 1) / CHUNK, FILL_T, 0, stream>>>(src, dst, gcur, edata, nE, nbk);
        csr_kernel<<<nbk, CSR_T, 0, stream>>>(edata, boff, off, perm, n, nE);

        const int g4 = (n * 4 + 255) / 256;
        const int g2 = (n * 2 + 255) / 256;
        // layer 1: h1b = bf16(leaky(agg(xb) @ W1 + b1))
        gather_dense_kernel<false><<<g4, 256, 0, stream>>>(xb, perm, off, W1, b1, nullptr, h1b, n);
        // layer 2 (+W3 fused): t3b = bf16(leaky(agg(h1b) @ W2 + b2) @ W3)
        gather_dense_kernel<true><<<g4, 256, 0, stream>>>(h1b, perm, off, W2, b2, W3, t3b, n);
        // layer 3: out = agg(t3b) + b3   (fp32 output)
        gather16_kernel<<<g2, 256, 0, stream>>>(t3b, perm, off, b3, out, n);
    } else {
        const int BLK = 256;
        const int node_grid = (n + BLK - 1) / BLK;
        float* agg = (float*)d_ws;
        float* h   = agg + (size_t)n * 32;
        zerof_kernel<<<(n * 32 + BLK - 1) / BLK, BLK, 0, stream>>>(agg, n * 32);
        scatter_kernel<32><<<((size_t)nE * 32 + BLK - 1) / BLK, BLK, 0, stream>>>(x, src, dst, agg, nE);
        dense_bias_kernel<32, 32, true><<<node_grid, BLK, 0, stream>>>(agg, W1, b1, h, n);
        zerof_kernel<<<(n * 32 + BLK - 1) / BLK, BLK, 0, stream>>>(agg, n * 32);
        scatter_kernel<32><<<((size_t)nE * 32 + BLK - 1) / BLK, BLK, 0, stream>>>(h, src, dst, agg, nE);
        dense_bias_kernel<32, 32, true><<<node_grid, BLK, 0, stream>>>(agg, W2, b2, h, n);
        dense_kernel<32, 16><<<node_grid, BLK, 0, stream>>>(h, W3, agg, n);
        init_out_kernel<<<(n * 16 + BLK - 1) / BLK, BLK, 0, stream>>>(out, b3, n * 16);
        scatter_kernel<16><<<((size_t)nE * 16 + BLK - 1) / BLK, BLK, 0, stream>>>(agg, src, dst, out, nE);
    }
}